// Round 17
// baseline (136.845 us; speedup 1.0000x reference)
//
#include <hip/hip_runtime.h>
#include <hip/hip_bf16.h>

// Problem constants
#define B_      4
#define T_      1024
#define NTOK    4096      // B*T
#define D_      512
#define E_      10
#define H_      2048
#define LIN_    928
#define TOPK    2
#define BM      128       // GEMM row tile (per-expert padding granule)
#define ROWS_CAP 9472     // >= 73*128 (max tiles) with slack
#define TILES_CAP 74      // worst case: sum ceil(n_e/128) <= 73

typedef __bf16 bf16x8 __attribute__((ext_vector_type(8)));
typedef float  f32x4  __attribute__((ext_vector_type(4)));
typedef unsigned short ushort8 __attribute__((ext_vector_type(8)));

// ---- workspace layout (bytes) ----
// y partials (2 x bf16 9.7MB = 19.4MB) alias w1T (21MB): w1T dead after gemm1.
// logits scratch (328KB) aliases hid: consumed by route2 before gemm1 writes hid.
#define OFF_W1T   0ull
#define SZ_W1T    (10ull*2048*512*2)            // 20,971,520
#define OFF_W2T   (OFF_W1T + SZ_W1T)
#define SZ_W2T    SZ_W1T
#define OFF_XG    (OFF_W2T + SZ_W2T)            // 41,943,040
#define SZ_XG     ((size_t)ROWS_CAP*512*2)      // 9,699,328
#define OFF_HID   (OFF_XG + SZ_XG)              // 51,642,368
#define SZ_HID    ((size_t)ROWS_CAP*2048*2)     // 38,797,312
#define OFF_Y     OFF_W1T                       // 2 partials: 19,398,656 <= 21MB
#define OFF_TOKE  (OFF_HID + SZ_HID)            // 90,439,680
#define OFF_TOKG  (OFF_TOKE + 32768)
#define OFF_TROWS (OFF_TOKG + 32768)
#define OFF_RANK  (OFF_TROWS + 32768)
#define OFF_CNT   (OFF_RANK + 32768)
// total ~90.6 MB

static __device__ __forceinline__ unsigned short f2b(float f) {
  // fp32 -> bf16 round-to-nearest-even (finite values)
  unsigned int u = __float_as_uint(f);
  unsigned int r = (u + 0x7fffu + ((u >> 16) & 1u)) >> 16;
  return (unsigned short)r;
}

static __device__ __forceinline__ float b2f(unsigned short u) {
  return __uint_as_float(((unsigned int)u) << 16);
}

// exact-form gelu with fast erf (Abramowitz-Stegun 7.1.26, |err| < 1.5e-7)
static __device__ __forceinline__ float gelu_f(float v) {
  float z = fabsf(v) * 0.70710678118654752440f;
  float t = __builtin_amdgcn_rcpf(fmaf(0.3275911f, z, 1.f));
  float p = fmaf(1.061405429f, t, -1.453152027f);
  p = fmaf(p, t, 1.421413741f);
  p = fmaf(p, t, -0.284496736f);
  p = fmaf(p, t, 0.254829592f);
  p = p * t;
  float ex = __expf(-z * z);
  float er = fmaf(-p, ex, 1.f);          // erf(|v|/sqrt2)
  er = (v < 0.f) ? -er : er;
  return 0.5f * v * (1.f + er);
}

// async global -> LDS, 16B per lane; lds dest wave-uniform base (HW adds lane*16)
static __device__ __forceinline__ void gld16(const void* g, void* l) {
  __builtin_amdgcn_global_load_lds(
      (const __attribute__((address_space(1))) unsigned int*)g,
      (__attribute__((address_space(3))) unsigned int*)l, 16, 0, 0);
}

// ================= prep: router (blocks 0..511) + wconv1 + wconv2 =================
// router: TWO PASSES (Wg then Wn), acc[2][10] live -> <64 VGPR so the whole kernel
// gets 8 waves/SIMD (m69: occupancy halves at VGPR=64). Block 0 zeroes counts.
// wconv: 64x128 tile as two 32x128 halves through 16.5KB LDS.
struct WconvLds { float t[32][129]; };   // 16.5 KB

static __device__ __forceinline__ void wconv_body(
    const float* __restrict__ src, unsigned short* __restrict__ dst,
    int R, int C, int e, int bx, int by, int tid, WconvLds* W) {
  int c0 = bx << 7, r0 = by << 6;        // 128 cols, 64 rows (2 halves of 32)
  int rr = tid >> 5, cc4 = (tid & 31) << 2;
  int wrow = tid >> 1, rb = (tid & 1) << 4;   // write: dst row c0+wrow, 16 shorts
#pragma unroll
  for (int h = 0; h < 2; h++) {
    const float* s = src + ((size_t)e * R + r0 + h * 32 + rr) * C + c0 + cc4;
#pragma unroll
    for (int p = 0; p < 4; p++) {
      float4 v = *(const float4*)(s + (size_t)p * 8 * C);
      int row = rr + p * 8;
      W->t[row][cc4 + 0] = v.x; W->t[row][cc4 + 1] = v.y;
      W->t[row][cc4 + 2] = v.z; W->t[row][cc4 + 3] = v.w;
    }
    __syncthreads();
    ushort8 o0, o1;
#pragma unroll
    for (int i = 0; i < 8; i++) o0[i] = f2b(W->t[rb + i][wrow]);
#pragma unroll
    for (int i = 0; i < 8; i++) o1[i] = f2b(W->t[rb + 8 + i][wrow]);
    unsigned short* d = &dst[((size_t)e * C + c0 + wrow) * R + r0 + h * 32 + rb];
    *(ushort8*)&d[0] = o0;
    *(ushort8*)&d[8] = o1;
    __syncthreads();   // protect LDS reuse across halves
  }
}

__global__ __launch_bounds__(256, 8) void prep_k(
    const float* __restrict__ x, const float* __restrict__ dt,
    const float* __restrict__ dd, const float* __restrict__ dr,
    const float* __restrict__ de, const float* __restrict__ cemb,
    const int* __restrict__ city,
    const float* __restrict__ Wg, const float* __restrict__ Wn,
    const float* __restrict__ W1, const float* __restrict__ W2,
    unsigned short* __restrict__ w1T, unsigned short* __restrict__ w2T,
    float* __restrict__ logits_all, int* __restrict__ counts) {
  __shared__ WconvLds W;
  int bx = blockIdx.x;
  int tid = threadIdx.x;
  if (bx >= 512) {
    int idx = bx - 512;
    if (idx < 1280) {
      int e = idx >> 7, rem = idx & 127;
      wconv_body(W1, w1T, 512, 2048, e, rem & 15, rem >> 4, tid, &W);
    } else {
      idx -= 1280;
      int e = idx >> 7, rem = idx & 127;
      wconv_body(W2, w2T, 2048, 512, e, rem & 3, rem >> 2, tid, &W);
    }
    return;
  }
  // ---- router: 2 passes (Wg -> logits 0..9, Wn -> logits 10..19), 2 tokens/wave ----
  if (bx == 0 && tid < E_) counts[tid] = 0;   // replaces memset dispatch
  int lane = tid & 63;
  int gw = bx * 4 + (tid >> 6);            // global wave 0..2047
  int n0 = gw * 2;                         // 2 tokens per wave
  int cb = city[n0 >> 10];

#pragma unroll
  for (int half = 0; half < 2; half++) {
    const float* Wh = half ? Wn : Wg;
    float acc[2][10];
#pragma unroll
    for (int j = 0; j < 2; j++)
#pragma unroll
      for (int o = 0; o < 10; o++) acc[j][o] = 0.f;

    {  // city segment (cols 512..543)
      float hce = (lane < 32) ? cemb[cb * 32 + lane] : 0.f;
      int c = 512 + (lane & 31);
#pragma unroll
      for (int o = 0; o < 10; o++) {
        float w = Wh[o * LIN_ + c];
#pragma unroll
        for (int j = 0; j < 2; j++) acc[j][o] = fmaf(hce, w, acc[j][o]);
      }
    }
#pragma unroll
    for (int s = 0; s < 5; s++) {
      const float* hp; int Wd, cofs;
      if      (s == 0) { hp = x;  Wd = 512; cofs = 0;   }
      else if (s == 1) { hp = dt; Wd = 128; cofs = 544; }
      else if (s == 2) { hp = dd; Wd = 128; cofs = 672; }
      else if (s == 3) { hp = dr; Wd = 64;  cofs = 800; }
      else             { hp = de; Wd = 64;  cofs = 864; }
      for (int base = 0; base < Wd; base += 64) {
        int c = cofs + base + lane;
        float wv[10];
#pragma unroll
        for (int o = 0; o < 10; o++) wv[o] = Wh[o * LIN_ + c];
        float hv[2];
#pragma unroll
        for (int j = 0; j < 2; j++) hv[j] = hp[(size_t)(n0 + j) * Wd + base + lane];
#pragma unroll
        for (int j = 0; j < 2; j++)
#pragma unroll
          for (int o = 0; o < 10; o++) acc[j][o] = fmaf(hv[j], wv[o], acc[j][o]);
      }
    }
#pragma unroll
    for (int off = 1; off < 64; off <<= 1) {
#pragma unroll
      for (int j = 0; j < 2; j++)
#pragma unroll
        for (int o = 0; o < 10; o++) acc[j][o] += __shfl_xor(acc[j][o], off);
    }
#pragma unroll
    for (int j = 0; j < 2; j++) {
      float v = 0.f;
#pragma unroll
      for (int o = 0; o < 10; o++) if (lane == o) v = acc[j][o];
      if (lane < 10) logits_all[(size_t)(n0 + j) * 20 + half * 10 + lane] = v;
    }
  }
}

// ---------------- router epilogue: softmax/gate1, noisy top-2, decoupled ranks ----------------
__global__ __launch_bounds__(256) void route2_k(
    const float* __restrict__ logits_all,
    const float* __restrict__ bg, const float* __restrict__ bn,
    const float* __restrict__ noise,
    float* __restrict__ gate1, int* __restrict__ tok_e,
    float* __restrict__ tok_g, int* __restrict__ ranks,
    int* __restrict__ counts) {
  __shared__ int lcnt[E_], lbase[E_];
  int tid = threadIdx.x;
  if (tid < E_) lcnt[tid] = 0;
  __syncthreads();
  int n = blockIdx.x * 256 + tid;
  const float* p = &logits_all[(size_t)n * 20];
  float logits[E_], noisy[E_], ex[E_];
  float mx = -3.4e38f;
#pragma unroll
  for (int e = 0; e < E_; e++) { logits[e] = p[e] + bg[e]; mx = fmaxf(mx, logits[e]); }
  float s = 0.f;
#pragma unroll
  for (int e = 0; e < E_; e++) { ex[e] = expf(logits[e] - mx); s += ex[e]; }
  float invs = 1.f / s;
#pragma unroll
  for (int e = 0; e < E_; e++) gate1[(size_t)n * E_ + e] = ex[e] * invs;
#pragma unroll
  for (int e = 0; e < E_; e++) {
    float t = p[10 + e] + bn[e];
    float sp = (t > 20.f) ? t : log1pf(expf(t));   // softplus
    noisy[e] = logits[e] + noise[(size_t)n * E_ + e] * sp;
  }
  int i0 = 0; float v0 = noisy[0];
#pragma unroll
  for (int e = 1; e < E_; e++) if (noisy[e] > v0) { v0 = noisy[e]; i0 = e; }
  int i1 = -1; float v1 = -3.4e38f;
#pragma unroll
  for (int e = 0; e < E_; e++) if (e != i0 && noisy[e] > v1) { v1 = noisy[e]; i1 = e; }
  float ee = expf(v1 - v0);
  float g0 = 1.f / (1.f + ee);
  tok_e[2 * n] = i0; tok_e[2 * n + 1] = i1;
  tok_g[2 * n] = g0; tok_g[2 * n + 1] = ee * g0;
  int r0 = atomicAdd(&lcnt[i0], 1);
  int r1 = atomicAdd(&lcnt[i1], 1);
  __syncthreads();
  if (tid < E_) lbase[tid] = atomicAdd(&counts[tid], lcnt[tid]);
  __syncthreads();
  ranks[2 * n]     = lbase[i0] + r0;
  ranks[2 * n + 1] = lbase[i1] + r1;
}

// ---------------- scatter+gather (no atomics): row = prefix(counts, e) + rank ----------------
__global__ __launch_bounds__(256) void scatgath_k(
    const float* __restrict__ x, const int* __restrict__ tok_e,
    const int* __restrict__ ranks, const int* __restrict__ counts,
    int* __restrict__ token_rows, unsigned short* __restrict__ xg) {
  int n = blockIdx.x * 4 + (threadIdx.x >> 6);   // token
  int lane = threadIdx.x & 63;
  int e0 = tok_e[2 * n], e1 = tok_e[2 * n + 1];
  int off0 = 0, off1 = 0, off = 0;
#pragma unroll
  for (int k = 0; k < E_; k++) {
    if (k == e0) off0 = off;
    if (k == e1) off1 = off;
    off += ((counts[k] + BM - 1) / BM) * BM;
  }
  int p0 = off0 + ranks[2 * n];
  int p1 = off1 + ranks[2 * n + 1];
  if (lane == 0) { token_rows[2 * n] = p0; token_rows[2 * n + 1] = p1; }
  float4 a = *(const float4*)&x[(size_t)n * D_ + lane * 8];
  float4 b = *(const float4*)&x[(size_t)n * D_ + lane * 8 + 4];
  ushort8 o;
  o[0] = f2b(a.x); o[1] = f2b(a.y); o[2] = f2b(a.z); o[3] = f2b(a.w);
  o[4] = f2b(b.x); o[5] = f2b(b.y); o[6] = f2b(b.z); o[7] = f2b(b.w);
  *(ushort8*)&xg[(size_t)p0 * D_ + lane * 8] = o;
  *(ushort8*)&xg[(size_t)p1 * D_ + lane * 8] = o;
}

// ---------------- grouped GEMM: 8-wave, 3-buffer 2-deep prefetch, counted vmcnt ----------------
// 512 threads: wave grid 4(M)x2(N), wave tile 32x64 (acc 2x4); staging PS=2 issues/wave
// (rowb=(wid+8i)*16); vmcnt 4/2/0. 48KB LDS -> 3 blocks x 8 waves = 24 waves/CU.
// Split-K over grid.z. XCD swizzle (T1). Tile table inline from counts.
// MODE 0: bf16 gelu(acc+bias); MODE 1: bf16 partial acc -> outb + ks*ROWS_CAP*ND.
template<int KD, int ND, int BNT, int GX, int KS, int MODE>
__global__ __launch_bounds__(512) void gemm_k(
    const unsigned short* __restrict__ A, const unsigned short* __restrict__ BT,
    const float* __restrict__ bias, unsigned short* __restrict__ outb,
    const int* __restrict__ counts) {
  constexpr int KFULL = KD * KS;
  constexpr int BMT = 128;
  constexpr int WN = BNT / 2;                    // 64
  constexpr int FN = WN / 16;                    // 4
  constexpr int PS = (BMT + BNT) / 128;          // 2 stage issues per wave
  constexpr int NT = KD / 32;
  constexpr int BUFSZ = (BMT + BNT) * 32;        // shorts per buffer (16KB)
  // bijective XCD swizzle (nwg % 8 == 0: GX*TILES_CAP*KS)
  int nwg = GX * TILES_CAP * KS;
  int fid = (blockIdx.z * TILES_CAP + blockIdx.y) * GX + blockIdx.x;
  int w = (fid & 7) * (nwg >> 3) + (fid >> 3);
  int bxs = w % GX;
  int rem = w / GX;
  int bys = rem % TILES_CAP;
  int ks  = rem / TILES_CAP;
  // inline tile table from counts
  int e = -1, row0 = 0;
  {
    int off = 0, tt = 0;
#pragma unroll
    for (int k = 0; k < E_; k++) {
      int nt = (counts[k] + BM - 1) / BM;
      if (bys >= tt && bys < tt + nt) { e = k; row0 = off + (bys - tt) * BM; }
      tt += nt; off += nt * BM;
    }
  }
  if (e < 0) return;
  int n0 = bxs * BNT;
  int tid = threadIdx.x;
  int lane = tid & 63, wid = tid >> 6;           // wid 0..7
  int wr = wid >> 1, wc = wid & 1;               // 4x2 wave grid; wave tile 32x64
  __shared__ __align__(16) unsigned short LDS[3][BUFSZ];   // 48 KB
  f32x4 acc[2][FN] = {};
  const unsigned short* Ab = A + (size_t)row0 * KFULL + (size_t)ks * KD;
  const unsigned short* Bb = BT + ((size_t)e * ND + n0) * KFULL + (size_t)ks * KD;
  int lrow = lane >> 2, lcol = (lane & 3) * 8;
  int r = lane & 15, g8 = (lane >> 4) * 8;
  const unsigned short* gp[PS];
  int loff[PS];
#pragma unroll
  for (int i = 0; i < PS; i++) {
    int rowb = (wid + 8 * i) * 16;
    gp[i] = (rowb < BMT) ? Ab + (size_t)(rowb + lrow) * KFULL + lcol
                         : Bb + (size_t)(rowb - BMT + lrow) * KFULL + lcol;
    loff[i] = rowb * 32;
  }
  // stage K-step t into buffer buf; t compile-time -> gp[i]+t*32 folds into imm offset
  auto stage = [&](int buf, int t) {
    unsigned short* lb = &LDS[0][0] + buf * BUFSZ;
#pragma unroll
    for (int i = 0; i < PS; i++) gld16(gp[i] + t * 32, lb + loff[i]);
  };
  stage(0, 0); stage(1, 1);
#pragma unroll
  for (int t = 0; t < NT; ++t) {
    if (t + 2 < NT) {
      stage((t + 2) % 3, t + 2);
      asm volatile("s_waitcnt vmcnt(4)" ::: "memory");
    } else if (t + 2 == NT) {
      asm volatile("s_waitcnt vmcnt(2)" ::: "memory");
    } else {
      asm volatile("s_waitcnt vmcnt(0)" ::: "memory");
    }
    asm volatile("s_barrier" ::: "memory");
    const unsigned short* cb2 = &LDS[0][0] + (t % 3) * BUFSZ;   // compile-time base
    bf16x8 av[2], bv[FN];
#pragma unroll
    for (int mi = 0; mi < 2; mi++)
      av[mi] = *(const bf16x8*)&cb2[(wr * 32 + mi * 16 + r) * 32 + g8];
#pragma unroll
    for (int ni = 0; ni < FN; ni++)
      bv[ni] = *(const bf16x8*)&cb2[(BMT + wc * WN + ni * 16 + r) * 32 + g8];
#pragma unroll
    for (int mi = 0; mi < 2; mi++)
#pragma unroll
      for (int ni = 0; ni < FN; ni++)
        acc[mi][ni] = __builtin_amdgcn_mfma_f32_16x16x32_bf16(av[mi], bv[ni], acc[mi][ni], 0, 0, 0);
    asm volatile("s_barrier" ::: "memory");
  }
  // C/D layout (m89-verified): col = lane&15, row = (lane>>4)*4 + reg
  unsigned short* outp = outb + (size_t)ks * ROWS_CAP * ND;
  int rq = (lane >> 4) * 4;
#pragma unroll
  for (int mi = 0; mi < 2; mi++) {
#pragma unroll
    for (int ni = 0; ni < FN; ni++) {
      int col = n0 + wc * WN + ni * 16 + r;
      float bz = (MODE == 0) ? bias[e * ND + col] : 0.f;
#pragma unroll
      for (int q = 0; q < 4; q++) {
        int row = row0 + wr * 32 + mi * 16 + rq + q;
        float v = acc[mi][ni][q];
        if constexpr (MODE == 0) v = gelu_f(v + bz);
        outp[(size_t)row * ND + col] = f2b(v);
      }
    }
  }
}

// ---------------- combine: out[n] = sum_k g_k*(y0[r_k]+y1[r_k]+b2[e_k]) ----------------
__global__ void combine_k(const unsigned short* __restrict__ y, const float* __restrict__ b2,
                          const int* __restrict__ token_rows, const int* __restrict__ tok_e,
                          const float* __restrict__ tok_g, float* __restrict__ out) {
  const unsigned short* yB = y + (size_t)ROWS_CAP * D_;   // second K-split partial
  int gid = blockIdx.x * 256 + threadIdx.x;   // NTOK*64 = 262144 total, 8 cols each
  int n = gid >> 6;
  int c = (gid & 63) << 3;
  int r0 = token_rows[2 * n], r1 = token_rows[2 * n + 1];
  int e0 = tok_e[2 * n], e1 = tok_e[2 * n + 1];
  float g0 = tok_g[2 * n], g1 = tok_g[2 * n + 1];
  ushort8 y0a = *(const ushort8*)&y [(size_t)r0 * D_ + c];
  ushort8 y0b = *(const ushort8*)&yB[(size_t)r0 * D_ + c];
  ushort8 y1a = *(const ushort8*)&y [(size_t)r1 * D_ + c];
  ushort8 y1b = *(const ushort8*)&yB[(size_t)r1 * D_ + c];
  float ba[8], bb[8], o[8];
  *(float4*)&ba[0] = *(const float4*)&b2[e0 * D_ + c];
  *(float4*)&ba[4] = *(const float4*)&b2[e0 * D_ + c + 4];
  *(float4*)&bb[0] = *(const float4*)&b2[e1 * D_ + c];
  *(float4*)&bb[4] = *(const float4*)&b2[e1 * D_ + c + 4];
#pragma unroll
  for (int j = 0; j < 8; j++)
    o[j] = g0 * (b2f(y0a[j]) + b2f(y0b[j]) + ba[j]) +
           g1 * (b2f(y1a[j]) + b2f(y1b[j]) + bb[j]);
  *(float4*)&out[(size_t)n * D_ + c]     = *(float4*)&o[0];
  *(float4*)&out[(size_t)n * D_ + c + 4] = *(float4*)&o[4];
}

extern "C" void kernel_launch(void* const* d_in, const int* in_sizes, int n_in,
                              void* d_out, int out_size, void* d_ws, size_t ws_size,
                              hipStream_t stream) {
  const float* x     = (const float*)d_in[0];
  const float* dt    = (const float*)d_in[1];
  const float* dd    = (const float*)d_in[2];
  const float* dr    = (const float*)d_in[3];
  const float* de    = (const float*)d_in[4];
  const float* cemb  = (const float*)d_in[5];
  const float* Wg    = (const float*)d_in[6];
  const float* bg    = (const float*)d_in[7];
  const float* Wn    = (const float*)d_in[8];
  const float* bn    = (const float*)d_in[9];
  const float* W1    = (const float*)d_in[10];
  const float* b1    = (const float*)d_in[11];
  const float* W2    = (const float*)d_in[12];
  const float* b2    = (const float*)d_in[13];
  const float* noise = (const float*)d_in[14];
  const int*   city  = (const int*)d_in[15];

  float* out   = (float*)d_out;
  float* gate1 = out + (size_t)NTOK * D_;

  char* ws = (char*)d_ws;
  unsigned short* w1T  = (unsigned short*)(ws + OFF_W1T);  // [E][H][D] bf16
  unsigned short* w2T  = (unsigned short*)(ws + OFF_W2T);  // [E][D][H] bf16
  unsigned short* xg   = (unsigned short*)(ws + OFF_XG);   // [ROWS_CAP][D] bf16
  unsigned short* hid  = (unsigned short*)(ws + OFF_HID);  // [ROWS_CAP][H] bf16
  unsigned short* yb16 = (unsigned short*)(ws + OFF_Y);    // 2x [ROWS_CAP][D] bf16 (alias w1T)
  int*    tok_e       = (int*)(ws + OFF_TOKE);
  float*  tok_g       = (float*)(ws + OFF_TOKG);
  int*    token_rows  = (int*)(ws + OFF_TROWS);
  int*    ranks       = (int*)(ws + OFF_RANK);
  int*    counts      = (int*)(ws + OFF_CNT);
  float*  logits_all  = (float*)(ws + OFF_HID);            // aliased scratch (pre-gemm1)

  // router (512 blocks, 2-pass low-VGPR; block 0 zeroes counts) + wconv1 (1280) + wconv2 (1280)
  prep_k<<<3072, 256, 0, stream>>>(x, dt, dd, dr, de, cemb, city, Wg, Wn,
                                   W1, W2, w1T, w2T, logits_all, counts);
  route2_k<<<16, 256, 0, stream>>>(logits_all, bg, bn, noise, gate1, tok_e, tok_g,
                                   ranks, counts);
  scatgath_k<<<1024, 256, 0, stream>>>(x, tok_e, ranks, counts, token_rows, xg);
  gemm_k<512, 2048, 128, 16, 1, 0><<<dim3(16, TILES_CAP, 1), 512, 0, stream>>>(xg, w1T, b1, hid, counts);
  gemm_k<1024, 512, 128, 4, 2, 1><<<dim3(4, TILES_CAP, 2), 512, 0, stream>>>(hid, w2T, nullptr, yb16, counts);
  combine_k<<<1024, 256, 0, stream>>>(yb16, b2, token_rows, tok_e, tok_g, out);
}

// Round 18
// 123.953 us; speedup vs baseline: 1.1040x; 1.1040x over previous
//
#include <hip/hip_runtime.h>
#include <hip/hip_bf16.h>

// Problem constants
#define B_      4
#define T_      1024
#define NTOK    4096      // B*T
#define D_      512
#define E_      10
#define H_      2048
#define LIN_    928
#define TOPK    2
#define BM      128       // GEMM row tile (per-expert padding granule)
#define ROWS_CAP 9472     // >= 73*128 (max tiles) with slack
#define TILES_CAP 74      // worst case: sum ceil(n_e/128) <= 73

typedef __bf16 bf16x8 __attribute__((ext_vector_type(8)));
typedef float  f32x4  __attribute__((ext_vector_type(4)));
typedef unsigned short ushort8 __attribute__((ext_vector_type(8)));

// ---- workspace layout (bytes) ----
// y partials (2 x bf16 9.7MB = 19.4MB) alias w1T (21MB): w1T dead after gemm1.
// logits scratch (328KB) aliases hid: consumed by route2 before gemm1 writes hid.
#define OFF_W1T   0ull
#define SZ_W1T    (10ull*2048*512*2)            // 20,971,520
#define OFF_W2T   (OFF_W1T + SZ_W1T)
#define SZ_W2T    SZ_W1T
#define OFF_XG    (OFF_W2T + SZ_W2T)            // 41,943,040
#define SZ_XG     ((size_t)ROWS_CAP*512*2)      // 9,699,328
#define OFF_HID   (OFF_XG + SZ_XG)              // 51,642,368
#define SZ_HID    ((size_t)ROWS_CAP*2048*2)     // 38,797,312
#define OFF_Y     OFF_W1T                       // 2 partials: 19,398,656 <= 21MB
#define OFF_TOKE  (OFF_HID + SZ_HID)            // 90,439,680
#define OFF_TOKG  (OFF_TOKE + 32768)
#define OFF_TROWS (OFF_TOKG + 32768)
#define OFF_RANK  (OFF_TROWS + 32768)
#define OFF_CNT   (OFF_RANK + 32768)
// total ~90.6 MB

static __device__ __forceinline__ unsigned short f2b(float f) {
  // fp32 -> bf16 round-to-nearest-even (finite values)
  unsigned int u = __float_as_uint(f);
  unsigned int r = (u + 0x7fffu + ((u >> 16) & 1u)) >> 16;
  return (unsigned short)r;
}

static __device__ __forceinline__ float b2f(unsigned short u) {
  return __uint_as_float(((unsigned int)u) << 16);
}

// exact-form gelu with fast erf (Abramowitz-Stegun 7.1.26, |err| < 1.5e-7)
static __device__ __forceinline__ float gelu_f(float v) {
  float z = fabsf(v) * 0.70710678118654752440f;
  float t = __builtin_amdgcn_rcpf(fmaf(0.3275911f, z, 1.f));
  float p = fmaf(1.061405429f, t, -1.453152027f);
  p = fmaf(p, t, 1.421413741f);
  p = fmaf(p, t, -0.284496736f);
  p = fmaf(p, t, 0.254829592f);
  p = p * t;
  float ex = __expf(-z * z);
  float er = fmaf(-p, ex, 1.f);          // erf(|v|/sqrt2)
  er = (v < 0.f) ? -er : er;
  return 0.5f * v * (1.f + er);
}

// async global -> LDS, 16B per lane; lds dest wave-uniform base (HW adds lane*16)
static __device__ __forceinline__ void gld16(const void* g, void* l) {
  __builtin_amdgcn_global_load_lds(
      (const __attribute__((address_space(1))) unsigned int*)g,
      (__attribute__((address_space(3))) unsigned int*)l, 16, 0, 0);
}

// ================= wconv: standalone weight convert+transpose =================
// Separate kernel so its (low) VGPR allocation isn't inflated by the router:
// natural ~40 VGPR -> 8 waves/SIMD. 64x128 tile as two 32x128 halves, 16.5KB LDS.
struct WconvLds { float t[32][129]; };   // 16.5 KB

static __device__ __forceinline__ void wconv_body(
    const float* __restrict__ src, unsigned short* __restrict__ dst,
    int R, int C, int e, int bx, int by, int tid, WconvLds* W) {
  int c0 = bx << 7, r0 = by << 6;        // 128 cols, 64 rows (2 halves of 32)
  int rr = tid >> 5, cc4 = (tid & 31) << 2;
  int wrow = tid >> 1, rb = (tid & 1) << 4;   // write: dst row c0+wrow, 16 shorts
#pragma unroll
  for (int h = 0; h < 2; h++) {
    const float* s = src + ((size_t)e * R + r0 + h * 32 + rr) * C + c0 + cc4;
#pragma unroll
    for (int p = 0; p < 4; p++) {
      float4 v = *(const float4*)(s + (size_t)p * 8 * C);
      int row = rr + p * 8;
      W->t[row][cc4 + 0] = v.x; W->t[row][cc4 + 1] = v.y;
      W->t[row][cc4 + 2] = v.z; W->t[row][cc4 + 3] = v.w;
    }
    __syncthreads();
    ushort8 o0, o1;
#pragma unroll
    for (int i = 0; i < 8; i++) o0[i] = f2b(W->t[rb + i][wrow]);
#pragma unroll
    for (int i = 0; i < 8; i++) o1[i] = f2b(W->t[rb + 8 + i][wrow]);
    unsigned short* d = &dst[((size_t)e * C + c0 + wrow) * R + r0 + h * 32 + rb];
    *(ushort8*)&d[0] = o0;
    *(ushort8*)&d[8] = o1;
    __syncthreads();   // protect LDS reuse across halves
  }
}

__global__ __launch_bounds__(256) void wconv_k(
    const float* __restrict__ W1, const float* __restrict__ W2,
    unsigned short* __restrict__ w1T, unsigned short* __restrict__ w2T) {
  __shared__ WconvLds W;
  int idx = blockIdx.x;
  int tid = threadIdx.x;
  if (idx < 1280) {
    int e = idx >> 7, rem = idx & 127;
    wconv_body(W1, w1T, 512, 2048, e, rem & 15, rem >> 4, tid, &W);
  } else {
    idx -= 1280;
    int e = idx >> 7, rem = idx & 127;
    wconv_body(W2, w2T, 2048, 512, e, rem & 3, rem >> 2, tid, &W);
  }
}

// ================= router: standalone, single-pass (r16 body) =================
// Each wave computes 2 tokens x 20 raw sums (fp32). Block 0 zeroes counts.
__global__ __launch_bounds__(256) void router_k(
    const float* __restrict__ x, const float* __restrict__ dt,
    const float* __restrict__ dd, const float* __restrict__ dr,
    const float* __restrict__ de, const float* __restrict__ cemb,
    const int* __restrict__ city,
    const float* __restrict__ Wg, const float* __restrict__ Wn,
    float* __restrict__ logits_all, int* __restrict__ counts) {
  int bx = blockIdx.x;
  int tid = threadIdx.x;
  if (bx == 0 && tid < E_) counts[tid] = 0;   // replaces memset dispatch
  int lane = tid & 63;
  int gw = bx * 4 + (tid >> 6);            // global wave 0..2047
  int n0 = gw * 2;                         // 2 tokens per wave
  int cb = city[n0 >> 10];

  float acc[2][20];
#pragma unroll
  for (int j = 0; j < 2; j++)
#pragma unroll
    for (int o = 0; o < 20; o++) acc[j][o] = 0.f;

  {  // city segment (cols 512..543)
    float hce = (lane < 32) ? cemb[cb * 32 + lane] : 0.f;
    int c = 512 + (lane & 31);
#pragma unroll
    for (int o = 0; o < 10; o++) {
      float wg = Wg[o * LIN_ + c];
      float wn = Wn[o * LIN_ + c];
#pragma unroll
      for (int j = 0; j < 2; j++) {
        acc[j][o]      = fmaf(hce, wg, acc[j][o]);
        acc[j][10 + o] = fmaf(hce, wn, acc[j][10 + o]);
      }
    }
  }
#pragma unroll
  for (int s = 0; s < 5; s++) {
    const float* hp; int Wd, cofs;
    if      (s == 0) { hp = x;  Wd = 512; cofs = 0;   }
    else if (s == 1) { hp = dt; Wd = 128; cofs = 544; }
    else if (s == 2) { hp = dd; Wd = 128; cofs = 672; }
    else if (s == 3) { hp = dr; Wd = 64;  cofs = 800; }
    else             { hp = de; Wd = 64;  cofs = 864; }
    for (int base = 0; base < Wd; base += 64) {
      int c = cofs + base + lane;
      float wv[20];
#pragma unroll
      for (int o = 0; o < 10; o++) {
        wv[o]      = Wg[o * LIN_ + c];
        wv[10 + o] = Wn[o * LIN_ + c];
      }
      float hv[2];
#pragma unroll
      for (int j = 0; j < 2; j++) hv[j] = hp[(size_t)(n0 + j) * Wd + base + lane];
#pragma unroll
      for (int j = 0; j < 2; j++)
#pragma unroll
        for (int o = 0; o < 20; o++) acc[j][o] = fmaf(hv[j], wv[o], acc[j][o]);
    }
  }
#pragma unroll
  for (int off = 1; off < 64; off <<= 1) {
#pragma unroll
    for (int j = 0; j < 2; j++)
#pragma unroll
      for (int o = 0; o < 20; o++) acc[j][o] += __shfl_xor(acc[j][o], off);
  }
#pragma unroll
  for (int j = 0; j < 2; j++) {
    float v = 0.f;
#pragma unroll
    for (int o = 0; o < 20; o++) if (lane == o) v = acc[j][o];
    if (lane < 20) logits_all[(size_t)(n0 + j) * 20 + lane] = v;
  }
}

// ---------------- router epilogue: softmax/gate1, noisy top-2, decoupled ranks ----------------
__global__ __launch_bounds__(256) void route2_k(
    const float* __restrict__ logits_all,
    const float* __restrict__ bg, const float* __restrict__ bn,
    const float* __restrict__ noise,
    float* __restrict__ gate1, int* __restrict__ tok_e,
    float* __restrict__ tok_g, int* __restrict__ ranks,
    int* __restrict__ counts) {
  __shared__ int lcnt[E_], lbase[E_];
  int tid = threadIdx.x;
  if (tid < E_) lcnt[tid] = 0;
  __syncthreads();
  int n = blockIdx.x * 256 + tid;
  const float* p = &logits_all[(size_t)n * 20];
  float logits[E_], noisy[E_], ex[E_];
  float mx = -3.4e38f;
#pragma unroll
  for (int e = 0; e < E_; e++) { logits[e] = p[e] + bg[e]; mx = fmaxf(mx, logits[e]); }
  float s = 0.f;
#pragma unroll
  for (int e = 0; e < E_; e++) { ex[e] = expf(logits[e] - mx); s += ex[e]; }
  float invs = 1.f / s;
#pragma unroll
  for (int e = 0; e < E_; e++) gate1[(size_t)n * E_ + e] = ex[e] * invs;
#pragma unroll
  for (int e = 0; e < E_; e++) {
    float t = p[10 + e] + bn[e];
    float sp = (t > 20.f) ? t : log1pf(expf(t));   // softplus
    noisy[e] = logits[e] + noise[(size_t)n * E_ + e] * sp;
  }
  int i0 = 0; float v0 = noisy[0];
#pragma unroll
  for (int e = 1; e < E_; e++) if (noisy[e] > v0) { v0 = noisy[e]; i0 = e; }
  int i1 = -1; float v1 = -3.4e38f;
#pragma unroll
  for (int e = 0; e < E_; e++) if (e != i0 && noisy[e] > v1) { v1 = noisy[e]; i1 = e; }
  float ee = expf(v1 - v0);
  float g0 = 1.f / (1.f + ee);
  tok_e[2 * n] = i0; tok_e[2 * n + 1] = i1;
  tok_g[2 * n] = g0; tok_g[2 * n + 1] = ee * g0;
  int r0 = atomicAdd(&lcnt[i0], 1);
  int r1 = atomicAdd(&lcnt[i1], 1);
  __syncthreads();
  if (tid < E_) lbase[tid] = atomicAdd(&counts[tid], lcnt[tid]);
  __syncthreads();
  ranks[2 * n]     = lbase[i0] + r0;
  ranks[2 * n + 1] = lbase[i1] + r1;
}

// ---------------- scatter+gather (no atomics): row = prefix(counts, e) + rank ----------------
__global__ __launch_bounds__(256) void scatgath_k(
    const float* __restrict__ x, const int* __restrict__ tok_e,
    const int* __restrict__ ranks, const int* __restrict__ counts,
    int* __restrict__ token_rows, unsigned short* __restrict__ xg) {
  int n = blockIdx.x * 4 + (threadIdx.x >> 6);   // token
  int lane = threadIdx.x & 63;
  int e0 = tok_e[2 * n], e1 = tok_e[2 * n + 1];
  int off0 = 0, off1 = 0, off = 0;
#pragma unroll
  for (int k = 0; k < E_; k++) {
    if (k == e0) off0 = off;
    if (k == e1) off1 = off;
    off += ((counts[k] + BM - 1) / BM) * BM;
  }
  int p0 = off0 + ranks[2 * n];
  int p1 = off1 + ranks[2 * n + 1];
  if (lane == 0) { token_rows[2 * n] = p0; token_rows[2 * n + 1] = p1; }
  float4 a = *(const float4*)&x[(size_t)n * D_ + lane * 8];
  float4 b = *(const float4*)&x[(size_t)n * D_ + lane * 8 + 4];
  ushort8 o;
  o[0] = f2b(a.x); o[1] = f2b(a.y); o[2] = f2b(a.z); o[3] = f2b(a.w);
  o[4] = f2b(b.x); o[5] = f2b(b.y); o[6] = f2b(b.z); o[7] = f2b(b.w);
  *(ushort8*)&xg[(size_t)p0 * D_ + lane * 8] = o;
  *(ushort8*)&xg[(size_t)p1 * D_ + lane * 8] = o;
}

// ---------------- grouped GEMM: 8-wave, 3-buffer 2-deep prefetch, counted vmcnt ----------------
// 512 threads: wave grid 4(M)x2(N), wave tile 32x64 (acc 2x4); staging PS=2 issues/wave
// (rowb=(wid+8i)*16); vmcnt 4/2/0. 48KB LDS -> 3 blocks x 8 waves = 24 waves/CU.
// Split-K over grid.z. XCD swizzle (T1). Tile table inline from counts.
// MODE 0: bf16 gelu(acc+bias); MODE 1: bf16 partial acc -> outb + ks*ROWS_CAP*ND.
template<int KD, int ND, int BNT, int GX, int KS, int MODE>
__global__ __launch_bounds__(512) void gemm_k(
    const unsigned short* __restrict__ A, const unsigned short* __restrict__ BT,
    const float* __restrict__ bias, unsigned short* __restrict__ outb,
    const int* __restrict__ counts) {
  constexpr int KFULL = KD * KS;
  constexpr int BMT = 128;
  constexpr int WN = BNT / 2;                    // 64
  constexpr int FN = WN / 16;                    // 4
  constexpr int PS = (BMT + BNT) / 128;          // 2 stage issues per wave
  constexpr int NT = KD / 32;
  constexpr int BUFSZ = (BMT + BNT) * 32;        // shorts per buffer (16KB)
  // bijective XCD swizzle (nwg % 8 == 0: GX*TILES_CAP*KS)
  int nwg = GX * TILES_CAP * KS;
  int fid = (blockIdx.z * TILES_CAP + blockIdx.y) * GX + blockIdx.x;
  int w = (fid & 7) * (nwg >> 3) + (fid >> 3);
  int bxs = w % GX;
  int rem = w / GX;
  int bys = rem % TILES_CAP;
  int ks  = rem / TILES_CAP;
  // inline tile table from counts
  int e = -1, row0 = 0;
  {
    int off = 0, tt = 0;
#pragma unroll
    for (int k = 0; k < E_; k++) {
      int nt = (counts[k] + BM - 1) / BM;
      if (bys >= tt && bys < tt + nt) { e = k; row0 = off + (bys - tt) * BM; }
      tt += nt; off += nt * BM;
    }
  }
  if (e < 0) return;
  int n0 = bxs * BNT;
  int tid = threadIdx.x;
  int lane = tid & 63, wid = tid >> 6;           // wid 0..7
  int wr = wid >> 1, wc = wid & 1;               // 4x2 wave grid; wave tile 32x64
  __shared__ __align__(16) unsigned short LDS[3][BUFSZ];   // 48 KB
  f32x4 acc[2][FN] = {};
  const unsigned short* Ab = A + (size_t)row0 * KFULL + (size_t)ks * KD;
  const unsigned short* Bb = BT + ((size_t)e * ND + n0) * KFULL + (size_t)ks * KD;
  int lrow = lane >> 2, lcol = (lane & 3) * 8;
  int r = lane & 15, g8 = (lane >> 4) * 8;
  const unsigned short* gp[PS];
  int loff[PS];
#pragma unroll
  for (int i = 0; i < PS; i++) {
    int rowb = (wid + 8 * i) * 16;
    gp[i] = (rowb < BMT) ? Ab + (size_t)(rowb + lrow) * KFULL + lcol
                         : Bb + (size_t)(rowb - BMT + lrow) * KFULL + lcol;
    loff[i] = rowb * 32;
  }
  // stage K-step t into buffer buf; t compile-time -> gp[i]+t*32 folds into imm offset
  auto stage = [&](int buf, int t) {
    unsigned short* lb = &LDS[0][0] + buf * BUFSZ;
#pragma unroll
    for (int i = 0; i < PS; i++) gld16(gp[i] + t * 32, lb + loff[i]);
  };
  stage(0, 0); stage(1, 1);
#pragma unroll
  for (int t = 0; t < NT; ++t) {
    if (t + 2 < NT) {
      stage((t + 2) % 3, t + 2);
      asm volatile("s_waitcnt vmcnt(4)" ::: "memory");
    } else if (t + 2 == NT) {
      asm volatile("s_waitcnt vmcnt(2)" ::: "memory");
    } else {
      asm volatile("s_waitcnt vmcnt(0)" ::: "memory");
    }
    asm volatile("s_barrier" ::: "memory");
    const unsigned short* cb2 = &LDS[0][0] + (t % 3) * BUFSZ;   // compile-time base
    bf16x8 av[2], bv[FN];
#pragma unroll
    for (int mi = 0; mi < 2; mi++)
      av[mi] = *(const bf16x8*)&cb2[(wr * 32 + mi * 16 + r) * 32 + g8];
#pragma unroll
    for (int ni = 0; ni < FN; ni++)
      bv[ni] = *(const bf16x8*)&cb2[(BMT + wc * WN + ni * 16 + r) * 32 + g8];
#pragma unroll
    for (int mi = 0; mi < 2; mi++)
#pragma unroll
      for (int ni = 0; ni < FN; ni++)
        acc[mi][ni] = __builtin_amdgcn_mfma_f32_16x16x32_bf16(av[mi], bv[ni], acc[mi][ni], 0, 0, 0);
    asm volatile("s_barrier" ::: "memory");
  }
  // C/D layout (m89-verified): col = lane&15, row = (lane>>4)*4 + reg
  unsigned short* outp = outb + (size_t)ks * ROWS_CAP * ND;
  int rq = (lane >> 4) * 4;
#pragma unroll
  for (int mi = 0; mi < 2; mi++) {
#pragma unroll
    for (int ni = 0; ni < FN; ni++) {
      int col = n0 + wc * WN + ni * 16 + r;
      float bz = (MODE == 0) ? bias[e * ND + col] : 0.f;
#pragma unroll
      for (int q = 0; q < 4; q++) {
        int row = row0 + wr * 32 + mi * 16 + rq + q;
        float v = acc[mi][ni][q];
        if constexpr (MODE == 0) v = gelu_f(v + bz);
        outp[(size_t)row * ND + col] = f2b(v);
      }
    }
  }
}

// ---------------- combine: out[n] = sum_k g_k*(y0[r_k]+y1[r_k]+b2[e_k]) ----------------
__global__ void combine_k(const unsigned short* __restrict__ y, const float* __restrict__ b2,
                          const int* __restrict__ token_rows, const int* __restrict__ tok_e,
                          const float* __restrict__ tok_g, float* __restrict__ out) {
  const unsigned short* yB = y + (size_t)ROWS_CAP * D_;   // second K-split partial
  int gid = blockIdx.x * 256 + threadIdx.x;   // NTOK*64 = 262144 total, 8 cols each
  int n = gid >> 6;
  int c = (gid & 63) << 3;
  int r0 = token_rows[2 * n], r1 = token_rows[2 * n + 1];
  int e0 = tok_e[2 * n], e1 = tok_e[2 * n + 1];
  float g0 = tok_g[2 * n], g1 = tok_g[2 * n + 1];
  ushort8 y0a = *(const ushort8*)&y [(size_t)r0 * D_ + c];
  ushort8 y0b = *(const ushort8*)&yB[(size_t)r0 * D_ + c];
  ushort8 y1a = *(const ushort8*)&y [(size_t)r1 * D_ + c];
  ushort8 y1b = *(const ushort8*)&yB[(size_t)r1 * D_ + c];
  float ba[8], bb[8], o[8];
  *(float4*)&ba[0] = *(const float4*)&b2[e0 * D_ + c];
  *(float4*)&ba[4] = *(const float4*)&b2[e0 * D_ + c + 4];
  *(float4*)&bb[0] = *(const float4*)&b2[e1 * D_ + c];
  *(float4*)&bb[4] = *(const float4*)&b2[e1 * D_ + c + 4];
#pragma unroll
  for (int j = 0; j < 8; j++)
    o[j] = g0 * (b2f(y0a[j]) + b2f(y0b[j]) + ba[j]) +
           g1 * (b2f(y1a[j]) + b2f(y1b[j]) + bb[j]);
  *(float4*)&out[(size_t)n * D_ + c]     = *(float4*)&o[0];
  *(float4*)&out[(size_t)n * D_ + c + 4] = *(float4*)&o[4];
}

extern "C" void kernel_launch(void* const* d_in, const int* in_sizes, int n_in,
                              void* d_out, int out_size, void* d_ws, size_t ws_size,
                              hipStream_t stream) {
  const float* x     = (const float*)d_in[0];
  const float* dt    = (const float*)d_in[1];
  const float* dd    = (const float*)d_in[2];
  const float* dr    = (const float*)d_in[3];
  const float* de    = (const float*)d_in[4];
  const float* cemb  = (const float*)d_in[5];
  const float* Wg    = (const float*)d_in[6];
  const float* bg    = (const float*)d_in[7];
  const float* Wn    = (const float*)d_in[8];
  const float* bn    = (const float*)d_in[9];
  const float* W1    = (const float*)d_in[10];
  const float* b1    = (const float*)d_in[11];
  const float* W2    = (const float*)d_in[12];
  const float* b2    = (const float*)d_in[13];
  const float* noise = (const float*)d_in[14];
  const int*   city  = (const int*)d_in[15];

  float* out   = (float*)d_out;
  float* gate1 = out + (size_t)NTOK * D_;

  char* ws = (char*)d_ws;
  unsigned short* w1T  = (unsigned short*)(ws + OFF_W1T);  // [E][H][D] bf16
  unsigned short* w2T  = (unsigned short*)(ws + OFF_W2T);  // [E][D][H] bf16
  unsigned short* xg   = (unsigned short*)(ws + OFF_XG);   // [ROWS_CAP][D] bf16
  unsigned short* hid  = (unsigned short*)(ws + OFF_HID);  // [ROWS_CAP][H] bf16
  unsigned short* yb16 = (unsigned short*)(ws + OFF_Y);    // 2x [ROWS_CAP][D] bf16 (alias w1T)
  int*    tok_e       = (int*)(ws + OFF_TOKE);
  float*  tok_g       = (float*)(ws + OFF_TOKG);
  int*    token_rows  = (int*)(ws + OFF_TROWS);
  int*    ranks       = (int*)(ws + OFF_RANK);
  int*    counts      = (int*)(ws + OFF_CNT);
  float*  logits_all  = (float*)(ws + OFF_HID);            // aliased scratch (pre-gemm1)

  router_k<<<512, 256, 0, stream>>>(x, dt, dd, dr, de, cemb, city, Wg, Wn,
                                    logits_all, counts);
  route2_k<<<16, 256, 0, stream>>>(logits_all, bg, bn, noise, gate1, tok_e, tok_g,
                                   ranks, counts);
  scatgath_k<<<1024, 256, 0, stream>>>(x, tok_e, ranks, counts, token_rows, xg);
  wconv_k<<<2560, 256, 0, stream>>>(W1, W2, w1T, w2T);
  gemm_k<512, 2048, 128, 16, 1, 0><<<dim3(16, TILES_CAP, 1), 512, 0, stream>>>(xg, w1T, b1, hid, counts);
  gemm_k<1024, 512, 128, 4, 2, 1><<<dim3(4, TILES_CAP, 2), 512, 0, stream>>>(hid, w2T, nullptr, yb16, counts);
  combine_k<<<1024, 256, 0, stream>>>(yb16, b2, token_rows, tok_e, tok_g, out);
}

// Round 19
// 114.457 us; speedup vs baseline: 1.1956x; 1.0830x over previous
//
#include <hip/hip_runtime.h>
#include <hip/hip_bf16.h>

// Problem constants
#define B_      4
#define T_      1024
#define NTOK    4096      // B*T
#define D_      512
#define E_      10
#define H_      2048
#define LIN_    928
#define TOPK    2
#define BM      128       // GEMM row tile (per-expert padding granule)
#define ROWS_CAP 9472     // >= 73*128 (max tiles) with slack
#define TILES_CAP 74      // worst case: sum ceil(n_e/128) <= 73

typedef __bf16 bf16x8 __attribute__((ext_vector_type(8)));
typedef float  f32x4  __attribute__((ext_vector_type(4)));
typedef unsigned short ushort8 __attribute__((ext_vector_type(8)));

// ---- workspace layout (bytes); ws_size = 256 MiB (fillBuffer evidence r18) ----
// logits scratch (328KB) aliases hid: consumed by route2 before gemm1 writes hid.
#define OFF_W1T   0ull
#define SZ_W1T    (10ull*2048*512*2)            // 20,971,520
#define OFF_W2T   (OFF_W1T + SZ_W1T)
#define SZ_W2T    SZ_W1T
#define OFF_XG    (OFF_W2T + SZ_W2T)            // 41,943,040
#define SZ_XG     ((size_t)ROWS_CAP*512*2)      // 9,699,328
#define OFF_HID   (OFF_XG + SZ_XG)              // 51,642,368
#define SZ_HID    ((size_t)ROWS_CAP*2048*2)     // 38,797,312
#define OFF_TOKE  (OFF_HID + SZ_HID)            // 90,439,680
#define OFF_TOKG  (OFF_TOKE + 32768)
#define OFF_TROWS (OFF_TOKG + 32768)
#define OFF_RANK  (OFF_TROWS + 32768)
#define OFF_CNT   (OFF_RANK + 32768)
#define OFF_YP    (OFF_CNT + 4096)              // 4 x bf16 partials [ROWS_CAP][D]
// total ~129.4 MB < 256 MiB

static __device__ __forceinline__ unsigned short f2b(float f) {
  // fp32 -> bf16 round-to-nearest-even (finite values)
  unsigned int u = __float_as_uint(f);
  unsigned int r = (u + 0x7fffu + ((u >> 16) & 1u)) >> 16;
  return (unsigned short)r;
}

static __device__ __forceinline__ float b2f(unsigned short u) {
  return __uint_as_float(((unsigned int)u) << 16);
}

// exact-form gelu with fast erf (Abramowitz-Stegun 7.1.26, |err| < 1.5e-7)
static __device__ __forceinline__ float gelu_f(float v) {
  float z = fabsf(v) * 0.70710678118654752440f;
  float t = __builtin_amdgcn_rcpf(fmaf(0.3275911f, z, 1.f));
  float p = fmaf(1.061405429f, t, -1.453152027f);
  p = fmaf(p, t, 1.421413741f);
  p = fmaf(p, t, -0.284496736f);
  p = fmaf(p, t, 0.254829592f);
  p = p * t;
  float ex = __expf(-z * z);
  float er = fmaf(-p, ex, 1.f);          // erf(|v|/sqrt2)
  er = (v < 0.f) ? -er : er;
  return 0.5f * v * (1.f + er);
}

// async global -> LDS, 16B per lane; lds dest wave-uniform base (HW adds lane*16)
static __device__ __forceinline__ void gld16(const void* g, void* l) {
  __builtin_amdgcn_global_load_lds(
      (const __attribute__((address_space(1))) unsigned int*)g,
      (__attribute__((address_space(3))) unsigned int*)l, 16, 0, 0);
}

// ================= prep: router (blocks 0..511) + wconv1 + wconv2 (r16 fused) =================
// Fusion lets router blocks run concurrently with wconv blocks (one stream would
// otherwise serialize them; r18 measured +10us from splitting). No launch_bounds cap:
// r17 showed forcing 32 VGPR spills wconv; r18 showed wconv is occupancy-insensitive.
struct WconvLds { float t[32][129]; };   // 16.5 KB

static __device__ __forceinline__ void wconv_body(
    const float* __restrict__ src, unsigned short* __restrict__ dst,
    int R, int C, int e, int bx, int by, int tid, WconvLds* W) {
  int c0 = bx << 7, r0 = by << 6;        // 128 cols, 64 rows (2 halves of 32)
  int rr = tid >> 5, cc4 = (tid & 31) << 2;
  int wrow = tid >> 1, rb = (tid & 1) << 4;   // write: dst row c0+wrow, 16 shorts
#pragma unroll
  for (int h = 0; h < 2; h++) {
    const float* s = src + ((size_t)e * R + r0 + h * 32 + rr) * C + c0 + cc4;
#pragma unroll
    for (int p = 0; p < 4; p++) {
      float4 v = *(const float4*)(s + (size_t)p * 8 * C);
      int row = rr + p * 8;
      W->t[row][cc4 + 0] = v.x; W->t[row][cc4 + 1] = v.y;
      W->t[row][cc4 + 2] = v.z; W->t[row][cc4 + 3] = v.w;
    }
    __syncthreads();
    ushort8 o0, o1;
#pragma unroll
    for (int i = 0; i < 8; i++) o0[i] = f2b(W->t[rb + i][wrow]);
#pragma unroll
    for (int i = 0; i < 8; i++) o1[i] = f2b(W->t[rb + 8 + i][wrow]);
    unsigned short* d = &dst[((size_t)e * C + c0 + wrow) * R + r0 + h * 32 + rb];
    *(ushort8*)&d[0] = o0;
    *(ushort8*)&d[8] = o1;
    __syncthreads();   // protect LDS reuse across halves
  }
}

__global__ __launch_bounds__(256) void prep_k(
    const float* __restrict__ x, const float* __restrict__ dt,
    const float* __restrict__ dd, const float* __restrict__ dr,
    const float* __restrict__ de, const float* __restrict__ cemb,
    const int* __restrict__ city,
    const float* __restrict__ Wg, const float* __restrict__ Wn,
    const float* __restrict__ W1, const float* __restrict__ W2,
    unsigned short* __restrict__ w1T, unsigned short* __restrict__ w2T,
    float* __restrict__ logits_all, int* __restrict__ counts) {
  __shared__ WconvLds W;
  int bx = blockIdx.x;
  int tid = threadIdx.x;
  if (bx >= 512) {
    int idx = bx - 512;
    if (idx < 1280) {
      int e = idx >> 7, rem = idx & 127;
      wconv_body(W1, w1T, 512, 2048, e, rem & 15, rem >> 4, tid, &W);
    } else {
      idx -= 1280;
      int e = idx >> 7, rem = idx & 127;
      wconv_body(W2, w2T, 2048, 512, e, rem & 3, rem >> 2, tid, &W);
    }
    return;
  }
  // ---- router: each wave computes 2 tokens x 20 raw sums ----
  if (bx == 0 && tid < E_) counts[tid] = 0;   // replaces memset dispatch
  int lane = tid & 63;
  int gw = bx * 4 + (tid >> 6);            // global wave 0..2047
  int n0 = gw * 2;                         // 2 tokens per wave
  int cb = city[n0 >> 10];

  float acc[2][20];
#pragma unroll
  for (int j = 0; j < 2; j++)
#pragma unroll
    for (int o = 0; o < 20; o++) acc[j][o] = 0.f;

  {  // city segment (cols 512..543)
    float hce = (lane < 32) ? cemb[cb * 32 + lane] : 0.f;
    int c = 512 + (lane & 31);
#pragma unroll
    for (int o = 0; o < 10; o++) {
      float wg = Wg[o * LIN_ + c];
      float wn = Wn[o * LIN_ + c];
#pragma unroll
      for (int j = 0; j < 2; j++) {
        acc[j][o]      = fmaf(hce, wg, acc[j][o]);
        acc[j][10 + o] = fmaf(hce, wn, acc[j][10 + o]);
      }
    }
  }
#pragma unroll
  for (int s = 0; s < 5; s++) {
    const float* hp; int Wd, cofs;
    if      (s == 0) { hp = x;  Wd = 512; cofs = 0;   }
    else if (s == 1) { hp = dt; Wd = 128; cofs = 544; }
    else if (s == 2) { hp = dd; Wd = 128; cofs = 672; }
    else if (s == 3) { hp = dr; Wd = 64;  cofs = 800; }
    else             { hp = de; Wd = 64;  cofs = 864; }
    for (int base = 0; base < Wd; base += 64) {
      int c = cofs + base + lane;
      float wv[20];
#pragma unroll
      for (int o = 0; o < 10; o++) {
        wv[o]      = Wg[o * LIN_ + c];
        wv[10 + o] = Wn[o * LIN_ + c];
      }
      float hv[2];
#pragma unroll
      for (int j = 0; j < 2; j++) hv[j] = hp[(size_t)(n0 + j) * Wd + base + lane];
#pragma unroll
      for (int j = 0; j < 2; j++)
#pragma unroll
        for (int o = 0; o < 20; o++) acc[j][o] = fmaf(hv[j], wv[o], acc[j][o]);
    }
  }
#pragma unroll
  for (int off = 1; off < 64; off <<= 1) {
#pragma unroll
    for (int j = 0; j < 2; j++)
#pragma unroll
      for (int o = 0; o < 20; o++) acc[j][o] += __shfl_xor(acc[j][o], off);
  }
#pragma unroll
  for (int j = 0; j < 2; j++) {
    float v = 0.f;
#pragma unroll
    for (int o = 0; o < 20; o++) if (lane == o) v = acc[j][o];
    if (lane < 20) logits_all[(size_t)(n0 + j) * 20 + lane] = v;
  }
}

// ---------------- router epilogue: softmax/gate1, noisy top-2, decoupled ranks ----------------
__global__ __launch_bounds__(256) void route2_k(
    const float* __restrict__ logits_all,
    const float* __restrict__ bg, const float* __restrict__ bn,
    const float* __restrict__ noise,
    float* __restrict__ gate1, int* __restrict__ tok_e,
    float* __restrict__ tok_g, int* __restrict__ ranks,
    int* __restrict__ counts) {
  __shared__ int lcnt[E_], lbase[E_];
  int tid = threadIdx.x;
  if (tid < E_) lcnt[tid] = 0;
  __syncthreads();
  int n = blockIdx.x * 256 + tid;
  const float* p = &logits_all[(size_t)n * 20];
  float logits[E_], noisy[E_], ex[E_];
  float mx = -3.4e38f;
#pragma unroll
  for (int e = 0; e < E_; e++) { logits[e] = p[e] + bg[e]; mx = fmaxf(mx, logits[e]); }
  float s = 0.f;
#pragma unroll
  for (int e = 0; e < E_; e++) { ex[e] = expf(logits[e] - mx); s += ex[e]; }
  float invs = 1.f / s;
#pragma unroll
  for (int e = 0; e < E_; e++) gate1[(size_t)n * E_ + e] = ex[e] * invs;
#pragma unroll
  for (int e = 0; e < E_; e++) {
    float t = p[10 + e] + bn[e];
    float sp = (t > 20.f) ? t : log1pf(expf(t));   // softplus
    noisy[e] = logits[e] + noise[(size_t)n * E_ + e] * sp;
  }
  int i0 = 0; float v0 = noisy[0];
#pragma unroll
  for (int e = 1; e < E_; e++) if (noisy[e] > v0) { v0 = noisy[e]; i0 = e; }
  int i1 = -1; float v1 = -3.4e38f;
#pragma unroll
  for (int e = 0; e < E_; e++) if (e != i0 && noisy[e] > v1) { v1 = noisy[e]; i1 = e; }
  float ee = expf(v1 - v0);
  float g0 = 1.f / (1.f + ee);
  tok_e[2 * n] = i0; tok_e[2 * n + 1] = i1;
  tok_g[2 * n] = g0; tok_g[2 * n + 1] = ee * g0;
  int r0 = atomicAdd(&lcnt[i0], 1);
  int r1 = atomicAdd(&lcnt[i1], 1);
  __syncthreads();
  if (tid < E_) lbase[tid] = atomicAdd(&counts[tid], lcnt[tid]);
  __syncthreads();
  ranks[2 * n]     = lbase[i0] + r0;
  ranks[2 * n + 1] = lbase[i1] + r1;
}

// ---------------- scatter+gather (no atomics): row = prefix(counts, e) + rank ----------------
__global__ __launch_bounds__(256) void scatgath_k(
    const float* __restrict__ x, const int* __restrict__ tok_e,
    const int* __restrict__ ranks, const int* __restrict__ counts,
    int* __restrict__ token_rows, unsigned short* __restrict__ xg) {
  int n = blockIdx.x * 4 + (threadIdx.x >> 6);   // token
  int lane = threadIdx.x & 63;
  int e0 = tok_e[2 * n], e1 = tok_e[2 * n + 1];
  int off0 = 0, off1 = 0, off = 0;
#pragma unroll
  for (int k = 0; k < E_; k++) {
    if (k == e0) off0 = off;
    if (k == e1) off1 = off;
    off += ((counts[k] + BM - 1) / BM) * BM;
  }
  int p0 = off0 + ranks[2 * n];
  int p1 = off1 + ranks[2 * n + 1];
  if (lane == 0) { token_rows[2 * n] = p0; token_rows[2 * n + 1] = p1; }
  float4 a = *(const float4*)&x[(size_t)n * D_ + lane * 8];
  float4 b = *(const float4*)&x[(size_t)n * D_ + lane * 8 + 4];
  ushort8 o;
  o[0] = f2b(a.x); o[1] = f2b(a.y); o[2] = f2b(a.z); o[3] = f2b(a.w);
  o[4] = f2b(b.x); o[5] = f2b(b.y); o[6] = f2b(b.z); o[7] = f2b(b.w);
  *(ushort8*)&xg[(size_t)p0 * D_ + lane * 8] = o;
  *(ushort8*)&xg[(size_t)p1 * D_ + lane * 8] = o;
}

// ---------------- grouped GEMM: 8-wave, 3-buffer 2-deep prefetch, counted vmcnt ----------------
// 512 threads: wave grid 4(M)x2(N), wave tile 32x64 (acc 2x4); staging PS=2 issues/wave
// (rowb=(wid+8i)*16); vmcnt 4/2/0. 48KB LDS -> 3 blocks x 8 waves = 24 waves/CU.
// Split-K over grid.z. XCD swizzle (T1). Tile table inline from counts.
// MODE 0: bf16 gelu(acc+bias); MODE 1: bf16 partial acc -> outb + ks*ROWS_CAP*ND.
template<int KD, int ND, int BNT, int GX, int KS, int MODE>
__global__ __launch_bounds__(512) void gemm_k(
    const unsigned short* __restrict__ A, const unsigned short* __restrict__ BT,
    const float* __restrict__ bias, unsigned short* __restrict__ outb,
    const int* __restrict__ counts) {
  constexpr int KFULL = KD * KS;
  constexpr int BMT = 128;
  constexpr int WN = BNT / 2;                    // 64
  constexpr int FN = WN / 16;                    // 4
  constexpr int PS = (BMT + BNT) / 128;          // 2 stage issues per wave
  constexpr int NT = KD / 32;
  constexpr int BUFSZ = (BMT + BNT) * 32;        // shorts per buffer (16KB)
  // bijective XCD swizzle (nwg % 8 == 0: GX*TILES_CAP*KS)
  int nwg = GX * TILES_CAP * KS;
  int fid = (blockIdx.z * TILES_CAP + blockIdx.y) * GX + blockIdx.x;
  int w = (fid & 7) * (nwg >> 3) + (fid >> 3);
  int bxs = w % GX;
  int rem = w / GX;
  int bys = rem % TILES_CAP;
  int ks  = rem / TILES_CAP;
  // inline tile table from counts
  int e = -1, row0 = 0;
  {
    int off = 0, tt = 0;
#pragma unroll
    for (int k = 0; k < E_; k++) {
      int nt = (counts[k] + BM - 1) / BM;
      if (bys >= tt && bys < tt + nt) { e = k; row0 = off + (bys - tt) * BM; }
      tt += nt; off += nt * BM;
    }
  }
  if (e < 0) return;
  int n0 = bxs * BNT;
  int tid = threadIdx.x;
  int lane = tid & 63, wid = tid >> 6;           // wid 0..7
  int wr = wid >> 1, wc = wid & 1;               // 4x2 wave grid; wave tile 32x64
  __shared__ __align__(16) unsigned short LDS[3][BUFSZ];   // 48 KB
  f32x4 acc[2][FN] = {};
  const unsigned short* Ab = A + (size_t)row0 * KFULL + (size_t)ks * KD;
  const unsigned short* Bb = BT + ((size_t)e * ND + n0) * KFULL + (size_t)ks * KD;
  int lrow = lane >> 2, lcol = (lane & 3) * 8;
  int r = lane & 15, g8 = (lane >> 4) * 8;
  const unsigned short* gp[PS];
  int loff[PS];
#pragma unroll
  for (int i = 0; i < PS; i++) {
    int rowb = (wid + 8 * i) * 16;
    gp[i] = (rowb < BMT) ? Ab + (size_t)(rowb + lrow) * KFULL + lcol
                         : Bb + (size_t)(rowb - BMT + lrow) * KFULL + lcol;
    loff[i] = rowb * 32;
  }
  // stage K-step t into buffer buf; t compile-time -> gp[i]+t*32 folds into imm offset
  auto stage = [&](int buf, int t) {
    unsigned short* lb = &LDS[0][0] + buf * BUFSZ;
#pragma unroll
    for (int i = 0; i < PS; i++) gld16(gp[i] + t * 32, lb + loff[i]);
  };
  stage(0, 0); stage(1, 1);
#pragma unroll
  for (int t = 0; t < NT; ++t) {
    if (t + 2 < NT) {
      stage((t + 2) % 3, t + 2);
      asm volatile("s_waitcnt vmcnt(4)" ::: "memory");
    } else if (t + 2 == NT) {
      asm volatile("s_waitcnt vmcnt(2)" ::: "memory");
    } else {
      asm volatile("s_waitcnt vmcnt(0)" ::: "memory");
    }
    asm volatile("s_barrier" ::: "memory");
    const unsigned short* cb2 = &LDS[0][0] + (t % 3) * BUFSZ;   // compile-time base
    bf16x8 av[2], bv[FN];
#pragma unroll
    for (int mi = 0; mi < 2; mi++)
      av[mi] = *(const bf16x8*)&cb2[(wr * 32 + mi * 16 + r) * 32 + g8];
#pragma unroll
    for (int ni = 0; ni < FN; ni++)
      bv[ni] = *(const bf16x8*)&cb2[(BMT + wc * WN + ni * 16 + r) * 32 + g8];
#pragma unroll
    for (int mi = 0; mi < 2; mi++)
#pragma unroll
      for (int ni = 0; ni < FN; ni++)
        acc[mi][ni] = __builtin_amdgcn_mfma_f32_16x16x32_bf16(av[mi], bv[ni], acc[mi][ni], 0, 0, 0);
    asm volatile("s_barrier" ::: "memory");
  }
  // C/D layout (m89-verified): col = lane&15, row = (lane>>4)*4 + reg
  unsigned short* outp = outb + (size_t)ks * ROWS_CAP * ND;
  int rq = (lane >> 4) * 4;
#pragma unroll
  for (int mi = 0; mi < 2; mi++) {
#pragma unroll
    for (int ni = 0; ni < FN; ni++) {
      int col = n0 + wc * WN + ni * 16 + r;
      float bz = (MODE == 0) ? bias[e * ND + col] : 0.f;
#pragma unroll
      for (int q = 0; q < 4; q++) {
        int row = row0 + wr * 32 + mi * 16 + rq + q;
        float v = acc[mi][ni][q];
        if constexpr (MODE == 0) v = gelu_f(v + bz);
        outp[(size_t)row * ND + col] = f2b(v);
      }
    }
  }
}

// ---------------- combine: out[n] = sum_k g_k*(sum_p yp[p][r_k] + b2[e_k]) ----------------
__global__ void combine_k(const unsigned short* __restrict__ y, const float* __restrict__ b2,
                          const int* __restrict__ token_rows, const int* __restrict__ tok_e,
                          const float* __restrict__ tok_g, float* __restrict__ out) {
  int gid = blockIdx.x * 256 + threadIdx.x;   // NTOK*64 = 262144 total, 8 cols each
  int n = gid >> 6;
  int c = (gid & 63) << 3;
  int r0 = token_rows[2 * n], r1 = token_rows[2 * n + 1];
  int e0 = tok_e[2 * n], e1 = tok_e[2 * n + 1];
  float g0 = tok_g[2 * n], g1 = tok_g[2 * n + 1];
  float s0[8] = {}, s1[8] = {};
#pragma unroll
  for (int p = 0; p < 4; p++) {
    const unsigned short* yp = y + (size_t)p * ROWS_CAP * D_;
    ushort8 a = *(const ushort8*)&yp[(size_t)r0 * D_ + c];
    ushort8 b = *(const ushort8*)&yp[(size_t)r1 * D_ + c];
#pragma unroll
    for (int j = 0; j < 8; j++) { s0[j] += b2f(a[j]); s1[j] += b2f(b[j]); }
  }
  float ba[8], bb[8], o[8];
  *(float4*)&ba[0] = *(const float4*)&b2[e0 * D_ + c];
  *(float4*)&ba[4] = *(const float4*)&b2[e0 * D_ + c + 4];
  *(float4*)&bb[0] = *(const float4*)&b2[e1 * D_ + c];
  *(float4*)&bb[4] = *(const float4*)&b2[e1 * D_ + c + 4];
#pragma unroll
  for (int j = 0; j < 8; j++)
    o[j] = g0 * (s0[j] + ba[j]) + g1 * (s1[j] + bb[j]);
  *(float4*)&out[(size_t)n * D_ + c]     = *(float4*)&o[0];
  *(float4*)&out[(size_t)n * D_ + c + 4] = *(float4*)&o[4];
}

extern "C" void kernel_launch(void* const* d_in, const int* in_sizes, int n_in,
                              void* d_out, int out_size, void* d_ws, size_t ws_size,
                              hipStream_t stream) {
  const float* x     = (const float*)d_in[0];
  const float* dt    = (const float*)d_in[1];
  const float* dd    = (const float*)d_in[2];
  const float* dr    = (const float*)d_in[3];
  const float* de    = (const float*)d_in[4];
  const float* cemb  = (const float*)d_in[5];
  const float* Wg    = (const float*)d_in[6];
  const float* bg    = (const float*)d_in[7];
  const float* Wn    = (const float*)d_in[8];
  const float* bn    = (const float*)d_in[9];
  const float* W1    = (const float*)d_in[10];
  const float* b1    = (const float*)d_in[11];
  const float* W2    = (const float*)d_in[12];
  const float* b2    = (const float*)d_in[13];
  const float* noise = (const float*)d_in[14];
  const int*   city  = (const int*)d_in[15];

  float* out   = (float*)d_out;
  float* gate1 = out + (size_t)NTOK * D_;

  char* ws = (char*)d_ws;
  unsigned short* w1T  = (unsigned short*)(ws + OFF_W1T);  // [E][H][D] bf16
  unsigned short* w2T  = (unsigned short*)(ws + OFF_W2T);  // [E][D][H] bf16
  unsigned short* xg   = (unsigned short*)(ws + OFF_XG);   // [ROWS_CAP][D] bf16
  unsigned short* hid  = (unsigned short*)(ws + OFF_HID);  // [ROWS_CAP][H] bf16
  unsigned short* yp   = (unsigned short*)(ws + OFF_YP);   // 4x [ROWS_CAP][D] bf16
  int*    tok_e       = (int*)(ws + OFF_TOKE);
  float*  tok_g       = (float*)(ws + OFF_TOKG);
  int*    token_rows  = (int*)(ws + OFF_TROWS);
  int*    ranks       = (int*)(ws + OFF_RANK);
  int*    counts      = (int*)(ws + OFF_CNT);
  float*  logits_all  = (float*)(ws + OFF_HID);            // aliased scratch (pre-gemm1)

  // router (512 blocks; block 0 zeroes counts) + wconv1 (1280) + wconv2 (1280) fused
  prep_k<<<3072, 256, 0, stream>>>(x, dt, dd, dr, de, cemb, city, Wg, Wn,
                                   W1, W2, w1T, w2T, logits_all, counts);
  route2_k<<<16, 256, 0, stream>>>(logits_all, bg, bn, noise, gate1, tok_e, tok_g,
                                   ranks, counts);
  scatgath_k<<<1024, 256, 0, stream>>>(x, tok_e, ranks, counts, token_rows, xg);
  gemm_k<512, 2048, 128, 16, 1, 0><<<dim3(16, TILES_CAP, 1), 512, 0, stream>>>(xg, w1T, b1, hid, counts);
  gemm_k<512, 512, 128, 4, 4, 1><<<dim3(4, TILES_CAP, 4), 512, 0, stream>>>(hid, w2T, nullptr, yp, counts);
  combine_k<<<1024, 256, 0, stream>>>(yp, b2, token_rows, tok_e, tok_g, out);
}

// Round 20
// 111.182 us; speedup vs baseline: 1.2308x; 1.0295x over previous
//
#include <hip/hip_runtime.h>
#include <hip/hip_bf16.h>

// Problem constants
#define B_      4
#define T_      1024
#define NTOK    4096      // B*T
#define D_      512
#define E_      10
#define H_      2048
#define LIN_    928
#define TOPK    2
#define BM      128       // GEMM row tile (per-expert padding granule)
#define ROWS_CAP 9472     // >= 73*128 (max tiles) with slack
#define TILES_CAP 74      // worst case: sum ceil(n_e/128) <= 73

typedef __bf16 bf16x8 __attribute__((ext_vector_type(8)));
typedef float  f32x4  __attribute__((ext_vector_type(4)));
typedef unsigned short ushort8 __attribute__((ext_vector_type(8)));

// ---- workspace layout (bytes); ws_size = 256 MiB (fillBuffer evidence r18) ----
// logits scratch (328KB) aliases hid: consumed by route2 before gemm1 writes hid.
#define OFF_W1T   0ull
#define SZ_W1T    (10ull*2048*512*2)            // 20,971,520
#define OFF_W2T   (OFF_W1T + SZ_W1T)
#define SZ_W2T    SZ_W1T
#define OFF_XG    (OFF_W2T + SZ_W2T)            // 41,943,040
#define SZ_XG     ((size_t)ROWS_CAP*512*2)      // 9,699,328
#define OFF_HID   (OFF_XG + SZ_XG)              // 51,642,368
#define SZ_HID    ((size_t)ROWS_CAP*2048*2)     // 38,797,312
#define OFF_TOKE  (OFF_HID + SZ_HID)            // 90,439,680
#define OFF_TOKG  (OFF_TOKE + 32768)
#define OFF_TROWS (OFF_TOKG + 32768)
#define OFF_RANK  (OFF_TROWS + 32768)
#define OFF_CNT   (OFF_RANK + 32768)
#define OFF_YP    (OFF_CNT + 4096)              // 4 x bf16 partials [ROWS_CAP][D]
// total ~129.4 MB < 256 MiB

static __device__ __forceinline__ unsigned short f2b(float f) {
  // fp32 -> bf16 round-to-nearest-even (finite values)
  unsigned int u = __float_as_uint(f);
  unsigned int r = (u + 0x7fffu + ((u >> 16) & 1u)) >> 16;
  return (unsigned short)r;
}

static __device__ __forceinline__ float b2f(unsigned short u) {
  return __uint_as_float(((unsigned int)u) << 16);
}

// exact-form gelu with fast erf (Abramowitz-Stegun 7.1.26, |err| < 1.5e-7)
static __device__ __forceinline__ float gelu_f(float v) {
  float z = fabsf(v) * 0.70710678118654752440f;
  float t = __builtin_amdgcn_rcpf(fmaf(0.3275911f, z, 1.f));
  float p = fmaf(1.061405429f, t, -1.453152027f);
  p = fmaf(p, t, 1.421413741f);
  p = fmaf(p, t, -0.284496736f);
  p = fmaf(p, t, 0.254829592f);
  p = p * t;
  float ex = __expf(-z * z);
  float er = fmaf(-p, ex, 1.f);          // erf(|v|/sqrt2)
  er = (v < 0.f) ? -er : er;
  return 0.5f * v * (1.f + er);
}

// async global -> LDS, 16B per lane; lds dest wave-uniform base (HW adds lane*16)
static __device__ __forceinline__ void gld16(const void* g, void* l) {
  __builtin_amdgcn_global_load_lds(
      (const __attribute__((address_space(1))) unsigned int*)g,
      (__attribute__((address_space(3))) unsigned int*)l, 16, 0, 0);
}

// ================= prep: router (blocks 0..511) + wconv1 + wconv2 (fused) =================
// wconv: barrier-free, LDS-free in-register 8x8 transpose. Each thread: 16 coalesced
// float4 loads -> register repack (compile-time indices) -> 8 ushort8 stores. Lane
// mapping a=(tid&7)|((tid>>7)<<3), cg=(tid>>3)&15: per store instruction a wave covers
// 8 dst rows x 128B contiguous (full L2 sectors). 128x128 tile per block.
static __device__ __forceinline__ void wconv_body(
    const float* __restrict__ src, unsigned short* __restrict__ dst,
    int R, int C, int e, int bx, int by, int tid) {
  int c0 = bx << 7, r0 = by << 7;        // 128 cols, 128 rows
  int cg = (tid >> 3) & 15;
  int a  = (tid & 7) | ((tid >> 7) << 3);
  int sr = r0 + a * 8, sc = c0 + cg * 8;
  const float* s = src + ((size_t)e * R + sr) * C + sc;
  float4 v[8][2];
#pragma unroll
  for (int r = 0; r < 8; r++) {
    v[r][0] = *(const float4*)(s + (size_t)r * C);
    v[r][1] = *(const float4*)(s + (size_t)r * C + 4);
  }
  unsigned short* d = dst + ((size_t)e * C + sc) * R + sr;
#pragma unroll
  for (int j = 0; j < 8; j++) {
    ushort8 o;
#pragma unroll
    for (int r = 0; r < 8; r++) {
      const float* vp = (const float*)&v[r][j >> 2];
      o[r] = f2b(vp[j & 3]);
    }
    *(ushort8*)&d[(size_t)j * R] = o;
  }
}

__global__ __launch_bounds__(256) void prep_k(
    const float* __restrict__ x, const float* __restrict__ dt,
    const float* __restrict__ dd, const float* __restrict__ dr,
    const float* __restrict__ de, const float* __restrict__ cemb,
    const int* __restrict__ city,
    const float* __restrict__ Wg, const float* __restrict__ Wn,
    const float* __restrict__ W1, const float* __restrict__ W2,
    unsigned short* __restrict__ w1T, unsigned short* __restrict__ w2T,
    float* __restrict__ logits_all, int* __restrict__ counts) {
  int bx = blockIdx.x;
  int tid = threadIdx.x;
  if (bx >= 512) {
    int idx = bx - 512;
    if (idx < 640) {
      int e = idx >> 6, rem = idx & 63;
      wconv_body(W1, w1T, 512, 2048, e, rem & 15, rem >> 4, tid);   // bx 0..15, by 0..3
    } else {
      idx -= 640;
      int e = idx >> 6, rem = idx & 63;
      wconv_body(W2, w2T, 2048, 512, e, rem & 3, rem >> 2, tid);    // bx 0..3, by 0..15
    }
    return;
  }
  // ---- router: each wave computes 2 tokens x 20 raw sums ----
  if (bx == 0 && tid < E_) counts[tid] = 0;   // replaces memset dispatch
  int lane = tid & 63;
  int gw = bx * 4 + (tid >> 6);            // global wave 0..2047
  int n0 = gw * 2;                         // 2 tokens per wave
  int cb = city[n0 >> 10];

  float acc[2][20];
#pragma unroll
  for (int j = 0; j < 2; j++)
#pragma unroll
    for (int o = 0; o < 20; o++) acc[j][o] = 0.f;

  {  // city segment (cols 512..543)
    float hce = (lane < 32) ? cemb[cb * 32 + lane] : 0.f;
    int c = 512 + (lane & 31);
#pragma unroll
    for (int o = 0; o < 10; o++) {
      float wg = Wg[o * LIN_ + c];
      float wn = Wn[o * LIN_ + c];
#pragma unroll
      for (int j = 0; j < 2; j++) {
        acc[j][o]      = fmaf(hce, wg, acc[j][o]);
        acc[j][10 + o] = fmaf(hce, wn, acc[j][10 + o]);
      }
    }
  }
#pragma unroll
  for (int s = 0; s < 5; s++) {
    const float* hp; int Wd, cofs;
    if      (s == 0) { hp = x;  Wd = 512; cofs = 0;   }
    else if (s == 1) { hp = dt; Wd = 128; cofs = 544; }
    else if (s == 2) { hp = dd; Wd = 128; cofs = 672; }
    else if (s == 3) { hp = dr; Wd = 64;  cofs = 800; }
    else             { hp = de; Wd = 64;  cofs = 864; }
    for (int base = 0; base < Wd; base += 64) {
      int c = cofs + base + lane;
      float wv[20];
#pragma unroll
      for (int o = 0; o < 10; o++) {
        wv[o]      = Wg[o * LIN_ + c];
        wv[10 + o] = Wn[o * LIN_ + c];
      }
      float hv[2];
#pragma unroll
      for (int j = 0; j < 2; j++) hv[j] = hp[(size_t)(n0 + j) * Wd + base + lane];
#pragma unroll
      for (int j = 0; j < 2; j++)
#pragma unroll
        for (int o = 0; o < 20; o++) acc[j][o] = fmaf(hv[j], wv[o], acc[j][o]);
    }
  }
#pragma unroll
  for (int off = 1; off < 64; off <<= 1) {
#pragma unroll
    for (int j = 0; j < 2; j++)
#pragma unroll
      for (int o = 0; o < 20; o++) acc[j][o] += __shfl_xor(acc[j][o], off);
  }
#pragma unroll
  for (int j = 0; j < 2; j++) {
    float v = 0.f;
#pragma unroll
    for (int o = 0; o < 20; o++) if (lane == o) v = acc[j][o];
    if (lane < 20) logits_all[(size_t)(n0 + j) * 20 + lane] = v;
  }
}

// ---------------- router epilogue: softmax/gate1, noisy top-2, decoupled ranks ----------------
__global__ __launch_bounds__(256) void route2_k(
    const float* __restrict__ logits_all,
    const float* __restrict__ bg, const float* __restrict__ bn,
    const float* __restrict__ noise,
    float* __restrict__ gate1, int* __restrict__ tok_e,
    float* __restrict__ tok_g, int* __restrict__ ranks,
    int* __restrict__ counts) {
  __shared__ int lcnt[E_], lbase[E_];
  int tid = threadIdx.x;
  if (tid < E_) lcnt[tid] = 0;
  __syncthreads();
  int n = blockIdx.x * 256 + tid;
  const float* p = &logits_all[(size_t)n * 20];
  float logits[E_], noisy[E_], ex[E_];
  float mx = -3.4e38f;
#pragma unroll
  for (int e = 0; e < E_; e++) { logits[e] = p[e] + bg[e]; mx = fmaxf(mx, logits[e]); }
  float s = 0.f;
#pragma unroll
  for (int e = 0; e < E_; e++) { ex[e] = expf(logits[e] - mx); s += ex[e]; }
  float invs = 1.f / s;
#pragma unroll
  for (int e = 0; e < E_; e++) gate1[(size_t)n * E_ + e] = ex[e] * invs;
#pragma unroll
  for (int e = 0; e < E_; e++) {
    float t = p[10 + e] + bn[e];
    float sp = (t > 20.f) ? t : log1pf(expf(t));   // softplus
    noisy[e] = logits[e] + noise[(size_t)n * E_ + e] * sp;
  }
  int i0 = 0; float v0 = noisy[0];
#pragma unroll
  for (int e = 1; e < E_; e++) if (noisy[e] > v0) { v0 = noisy[e]; i0 = e; }
  int i1 = -1; float v1 = -3.4e38f;
#pragma unroll
  for (int e = 0; e < E_; e++) if (e != i0 && noisy[e] > v1) { v1 = noisy[e]; i1 = e; }
  float ee = expf(v1 - v0);
  float g0 = 1.f / (1.f + ee);
  tok_e[2 * n] = i0; tok_e[2 * n + 1] = i1;
  tok_g[2 * n] = g0; tok_g[2 * n + 1] = ee * g0;
  int r0 = atomicAdd(&lcnt[i0], 1);
  int r1 = atomicAdd(&lcnt[i1], 1);
  __syncthreads();
  if (tid < E_) lbase[tid] = atomicAdd(&counts[tid], lcnt[tid]);
  __syncthreads();
  ranks[2 * n]     = lbase[i0] + r0;
  ranks[2 * n + 1] = lbase[i1] + r1;
}

// ---------------- scatter+gather (no atomics): row = prefix(counts, e) + rank ----------------
__global__ __launch_bounds__(256) void scatgath_k(
    const float* __restrict__ x, const int* __restrict__ tok_e,
    const int* __restrict__ ranks, const int* __restrict__ counts,
    int* __restrict__ token_rows, unsigned short* __restrict__ xg) {
  int n = blockIdx.x * 4 + (threadIdx.x >> 6);   // token
  int lane = threadIdx.x & 63;
  int e0 = tok_e[2 * n], e1 = tok_e[2 * n + 1];
  int off0 = 0, off1 = 0, off = 0;
#pragma unroll
  for (int k = 0; k < E_; k++) {
    if (k == e0) off0 = off;
    if (k == e1) off1 = off;
    off += ((counts[k] + BM - 1) / BM) * BM;
  }
  int p0 = off0 + ranks[2 * n];
  int p1 = off1 + ranks[2 * n + 1];
  if (lane == 0) { token_rows[2 * n] = p0; token_rows[2 * n + 1] = p1; }
  float4 a = *(const float4*)&x[(size_t)n * D_ + lane * 8];
  float4 b = *(const float4*)&x[(size_t)n * D_ + lane * 8 + 4];
  ushort8 o;
  o[0] = f2b(a.x); o[1] = f2b(a.y); o[2] = f2b(a.z); o[3] = f2b(a.w);
  o[4] = f2b(b.x); o[5] = f2b(b.y); o[6] = f2b(b.z); o[7] = f2b(b.w);
  *(ushort8*)&xg[(size_t)p0 * D_ + lane * 8] = o;
  *(ushort8*)&xg[(size_t)p1 * D_ + lane * 8] = o;
}

// ---------------- grouped GEMM: 8-wave, 3-buffer 2-deep prefetch, counted vmcnt ----------------
// 512 threads: wave grid 4(M)x2(N), wave tile 32x64 (acc 2x4); staging PS=2 issues/wave
// (rowb=(wid+8i)*16); vmcnt 4/2/0. 48KB LDS -> 3 blocks x 8 waves = 24 waves/CU.
// Split-K over grid.z. XCD swizzle (T1). Tile table inline from counts.
// MODE 0: bf16 gelu(acc+bias); MODE 1: bf16 partial acc -> outb + ks*ROWS_CAP*ND.
template<int KD, int ND, int BNT, int GX, int KS, int MODE>
__global__ __launch_bounds__(512) void gemm_k(
    const unsigned short* __restrict__ A, const unsigned short* __restrict__ BT,
    const float* __restrict__ bias, unsigned short* __restrict__ outb,
    const int* __restrict__ counts) {
  constexpr int KFULL = KD * KS;
  constexpr int BMT = 128;
  constexpr int WN = BNT / 2;                    // 64
  constexpr int FN = WN / 16;                    // 4
  constexpr int PS = (BMT + BNT) / 128;          // 2 stage issues per wave
  constexpr int NT = KD / 32;
  constexpr int BUFSZ = (BMT + BNT) * 32;        // shorts per buffer (16KB)
  // bijective XCD swizzle (nwg % 8 == 0: GX*TILES_CAP*KS)
  int nwg = GX * TILES_CAP * KS;
  int fid = (blockIdx.z * TILES_CAP + blockIdx.y) * GX + blockIdx.x;
  int w = (fid & 7) * (nwg >> 3) + (fid >> 3);
  int bxs = w % GX;
  int rem = w / GX;
  int bys = rem % TILES_CAP;
  int ks  = rem / TILES_CAP;
  // inline tile table from counts
  int e = -1, row0 = 0;
  {
    int off = 0, tt = 0;
#pragma unroll
    for (int k = 0; k < E_; k++) {
      int nt = (counts[k] + BM - 1) / BM;
      if (bys >= tt && bys < tt + nt) { e = k; row0 = off + (bys - tt) * BM; }
      tt += nt; off += nt * BM;
    }
  }
  if (e < 0) return;
  int n0 = bxs * BNT;
  int tid = threadIdx.x;
  int lane = tid & 63, wid = tid >> 6;           // wid 0..7
  int wr = wid >> 1, wc = wid & 1;               // 4x2 wave grid; wave tile 32x64
  __shared__ __align__(16) unsigned short LDS[3][BUFSZ];   // 48 KB
  f32x4 acc[2][FN] = {};
  const unsigned short* Ab = A + (size_t)row0 * KFULL + (size_t)ks * KD;
  const unsigned short* Bb = BT + ((size_t)e * ND + n0) * KFULL + (size_t)ks * KD;
  int lrow = lane >> 2, lcol = (lane & 3) * 8;
  int r = lane & 15, g8 = (lane >> 4) * 8;
  const unsigned short* gp[PS];
  int loff[PS];
#pragma unroll
  for (int i = 0; i < PS; i++) {
    int rowb = (wid + 8 * i) * 16;
    gp[i] = (rowb < BMT) ? Ab + (size_t)(rowb + lrow) * KFULL + lcol
                         : Bb + (size_t)(rowb - BMT + lrow) * KFULL + lcol;
    loff[i] = rowb * 32;
  }
  // stage K-step t into buffer buf; t compile-time -> gp[i]+t*32 folds into imm offset
  auto stage = [&](int buf, int t) {
    unsigned short* lb = &LDS[0][0] + buf * BUFSZ;
#pragma unroll
    for (int i = 0; i < PS; i++) gld16(gp[i] + t * 32, lb + loff[i]);
  };
  stage(0, 0); stage(1, 1);
#pragma unroll
  for (int t = 0; t < NT; ++t) {
    if (t + 2 < NT) {
      stage((t + 2) % 3, t + 2);
      asm volatile("s_waitcnt vmcnt(4)" ::: "memory");
    } else if (t + 2 == NT) {
      asm volatile("s_waitcnt vmcnt(2)" ::: "memory");
    } else {
      asm volatile("s_waitcnt vmcnt(0)" ::: "memory");
    }
    asm volatile("s_barrier" ::: "memory");
    const unsigned short* cb2 = &LDS[0][0] + (t % 3) * BUFSZ;   // compile-time base
    bf16x8 av[2], bv[FN];
#pragma unroll
    for (int mi = 0; mi < 2; mi++)
      av[mi] = *(const bf16x8*)&cb2[(wr * 32 + mi * 16 + r) * 32 + g8];
#pragma unroll
    for (int ni = 0; ni < FN; ni++)
      bv[ni] = *(const bf16x8*)&cb2[(BMT + wc * WN + ni * 16 + r) * 32 + g8];
#pragma unroll
    for (int mi = 0; mi < 2; mi++)
#pragma unroll
      for (int ni = 0; ni < FN; ni++)
        acc[mi][ni] = __builtin_amdgcn_mfma_f32_16x16x32_bf16(av[mi], bv[ni], acc[mi][ni], 0, 0, 0);
    asm volatile("s_barrier" ::: "memory");
  }
  // C/D layout (m89-verified): col = lane&15, row = (lane>>4)*4 + reg
  unsigned short* outp = outb + (size_t)ks * ROWS_CAP * ND;
  int rq = (lane >> 4) * 4;
#pragma unroll
  for (int mi = 0; mi < 2; mi++) {
#pragma unroll
    for (int ni = 0; ni < FN; ni++) {
      int col = n0 + wc * WN + ni * 16 + r;
      float bz = (MODE == 0) ? bias[e * ND + col] : 0.f;
#pragma unroll
      for (int q = 0; q < 4; q++) {
        int row = row0 + wr * 32 + mi * 16 + rq + q;
        float v = acc[mi][ni][q];
        if constexpr (MODE == 0) v = gelu_f(v + bz);
        outp[(size_t)row * ND + col] = f2b(v);
      }
    }
  }
}

// ---------------- combine: out[n] = sum_k g_k*(sum_p yp[p][r_k] + b2[e_k]) ----------------
__global__ void combine_k(const unsigned short* __restrict__ y, const float* __restrict__ b2,
                          const int* __restrict__ token_rows, const int* __restrict__ tok_e,
                          const float* __restrict__ tok_g, float* __restrict__ out) {
  int gid = blockIdx.x * 256 + threadIdx.x;   // NTOK*64 = 262144 total, 8 cols each
  int n = gid >> 6;
  int c = (gid & 63) << 3;
  int r0 = token_rows[2 * n], r1 = token_rows[2 * n + 1];
  int e0 = tok_e[2 * n], e1 = tok_e[2 * n + 1];
  float g0 = tok_g[2 * n], g1 = tok_g[2 * n + 1];
  float s0[8] = {}, s1[8] = {};
#pragma unroll
  for (int p = 0; p < 4; p++) {
    const unsigned short* yp = y + (size_t)p * ROWS_CAP * D_;
    ushort8 a = *(const ushort8*)&yp[(size_t)r0 * D_ + c];
    ushort8 b = *(const ushort8*)&yp[(size_t)r1 * D_ + c];
#pragma unroll
    for (int j = 0; j < 8; j++) { s0[j] += b2f(a[j]); s1[j] += b2f(b[j]); }
  }
  float ba[8], bb[8], o[8];
  *(float4*)&ba[0] = *(const float4*)&b2[e0 * D_ + c];
  *(float4*)&ba[4] = *(const float4*)&b2[e0 * D_ + c + 4];
  *(float4*)&bb[0] = *(const float4*)&b2[e1 * D_ + c];
  *(float4*)&bb[4] = *(const float4*)&b2[e1 * D_ + c + 4];
#pragma unroll
  for (int j = 0; j < 8; j++)
    o[j] = g0 * (s0[j] + ba[j]) + g1 * (s1[j] + bb[j]);
  *(float4*)&out[(size_t)n * D_ + c]     = *(float4*)&o[0];
  *(float4*)&out[(size_t)n * D_ + c + 4] = *(float4*)&o[4];
}

extern "C" void kernel_launch(void* const* d_in, const int* in_sizes, int n_in,
                              void* d_out, int out_size, void* d_ws, size_t ws_size,
                              hipStream_t stream) {
  const float* x     = (const float*)d_in[0];
  const float* dt    = (const float*)d_in[1];
  const float* dd    = (const float*)d_in[2];
  const float* dr    = (const float*)d_in[3];
  const float* de    = (const float*)d_in[4];
  const float* cemb  = (const float*)d_in[5];
  const float* Wg    = (const float*)d_in[6];
  const float* bg    = (const float*)d_in[7];
  const float* Wn    = (const float*)d_in[8];
  const float* bn    = (const float*)d_in[9];
  const float* W1    = (const float*)d_in[10];
  const float* b1    = (const float*)d_in[11];
  const float* W2    = (const float*)d_in[12];
  const float* b2    = (const float*)d_in[13];
  const float* noise = (const float*)d_in[14];
  const int*   city  = (const int*)d_in[15];

  float* out   = (float*)d_out;
  float* gate1 = out + (size_t)NTOK * D_;

  char* ws = (char*)d_ws;
  unsigned short* w1T  = (unsigned short*)(ws + OFF_W1T);  // [E][H][D] bf16
  unsigned short* w2T  = (unsigned short*)(ws + OFF_W2T);  // [E][D][H] bf16
  unsigned short* xg   = (unsigned short*)(ws + OFF_XG);   // [ROWS_CAP][D] bf16
  unsigned short* hid  = (unsigned short*)(ws + OFF_HID);  // [ROWS_CAP][H] bf16
  unsigned short* yp   = (unsigned short*)(ws + OFF_YP);   // 4x [ROWS_CAP][D] bf16
  int*    tok_e       = (int*)(ws + OFF_TOKE);
  float*  tok_g       = (float*)(ws + OFF_TOKG);
  int*    token_rows  = (int*)(ws + OFF_TROWS);
  int*    ranks       = (int*)(ws + OFF_RANK);
  int*    counts      = (int*)(ws + OFF_CNT);
  float*  logits_all  = (float*)(ws + OFF_HID);            // aliased scratch (pre-gemm1)

  // router (512 blocks; block 0 zeroes counts) + wconv1 (640) + wconv2 (640) fused
  prep_k<<<1792, 256, 0, stream>>>(x, dt, dd, dr, de, cemb, city, Wg, Wn,
                                   W1, W2, w1T, w2T, logits_all, counts);
  route2_k<<<16, 256, 0, stream>>>(logits_all, bg, bn, noise, gate1, tok_e, tok_g,
                                   ranks, counts);
  scatgath_k<<<1024, 256, 0, stream>>>(x, tok_e, ranks, counts, token_rows, xg);
  gemm_k<512, 2048, 128, 16, 1, 0><<<dim3(16, TILES_CAP, 1), 512, 0, stream>>>(xg, w1T, b1, hid, counts);
  gemm_k<512, 512, 128, 4, 4, 1><<<dim3(4, TILES_CAP, 4), 512, 0, stream>>>(hid, w2T, nullptr, yp, counts);
  combine_k<<<1024, 256, 0, stream>>>(yp, b2, token_rows, tok_e, tok_g, out);
}